// Round 2
// baseline (1566.791 us; speedup 1.0000x reference)
//
#include <hip/hip_runtime.h>

// ProgressiveWindowAttention — Swin-style window MHA.
// B=2048 windows, N=64 tokens, C=512, H=16 heads, HD=32, NW=64, W=8.
//
// Pipeline:
//   k0: cast x fp32 -> bf16                    (xb)
//   k1: transpose+cast qkv_w -> [1536][512] bf16 (wqkvT)   (B^T layout)
//   k2: transpose+cast proj_w -> [512][512] bf16 (wprojT)
//   k3: QKV GEMM  bf16 MFMA 128x128 tile, global_load_lds staging -> qkvb bf16
//   k4: per-(b,h) attention, fp32 VALU, K/V staged fp32 in LDS -> attnb bf16
//   k5: proj GEMM bf16 MFMA -> d_out fp32 (+bias)
//
// ws layout (needs ~539 MB):
//   [0, 402653184)            qkvb  [131072][1536] bf16
//   [402653184, 536870912)    xb    [131072][512]  bf16  (reused as attnb)
//   [536870912, 538443776)    wqkvT [1536][512]    bf16
//   [538443776, 538968064)    wprojT[512][512]     bf16

#define SCALE 0.17677669529663689f  // 32^-0.5

typedef __bf16 bf16x8 __attribute__((ext_vector_type(8)));
typedef float f32x4 __attribute__((ext_vector_type(4)));

__device__ __forceinline__ unsigned short f2bf(float f) {
  unsigned u = __builtin_bit_cast(unsigned, f);
  u += 0x7FFFu + ((u >> 16) & 1u);   // RNE
  return (unsigned short)(u >> 16);
}
__device__ __forceinline__ float bf2f(unsigned short s) {
  unsigned u = ((unsigned)s) << 16;
  return __builtin_bit_cast(float, u);
}

// ---------------- k0: cast x to bf16 (4 elems/thread) ----------------
__global__ __launch_bounds__(256) void cast_x_kernel(
    const float* __restrict__ x, unsigned short* __restrict__ xb) {
  int idx = blockIdx.x * 256 + threadIdx.x;
  float4 v = ((const float4*)x)[idx];
  ushort4 o;
  o.x = f2bf(v.x); o.y = f2bf(v.y); o.z = f2bf(v.z); o.w = f2bf(v.w);
  ((ushort4*)xb)[idx] = o;
}

// ------------- k1/k2: W [512][Nc] fp32 -> W^T [Nc][512] bf16 -------------
__global__ __launch_bounds__(256) void castT_kernel(
    const float* __restrict__ w, unsigned short* __restrict__ wT, int Nc) {
  int o = blockIdx.x * 256 + threadIdx.x;  // o = n*512 + k
  int n = o >> 9, k = o & 511;
  wT[o] = f2bf(w[(size_t)k * Nc + n]);
}

// ---------------- GEMM: A[M][512]bf16 @ Bt[NOUT][512]bf16 ----------------
// 128x128 tile, BK=64, 4 waves (2x2), each wave 64x64 = 4x4 frags of 16x16.
template <int NOUT, bool OUT_BF16>
__global__ __launch_bounds__(256) void gemm_kernel(
    const unsigned short* __restrict__ A, const unsigned short* __restrict__ Bt,
    const float* __restrict__ bias, void* __restrict__ out) {
  __shared__ __attribute__((aligned(16))) unsigned short As[128 * 64];
  __shared__ __attribute__((aligned(16))) unsigned short Bs[128 * 64];
  constexpr int NT = NOUT / 128;
  const int bid = blockIdx.x;
  const int mt = bid / NT, nt = bid % NT;
  const int tid = threadIdx.x;
  const int w = tid >> 6, l = tid & 63;
  const int wr = w >> 1, wc = w & 1;
  const int rl = l & 15, kg = l >> 4;

  f32x4 acc[4][4];
#pragma unroll
  for (int i = 0; i < 4; ++i)
#pragma unroll
    for (int j = 0; j < 4; ++j) acc[i][j] = (f32x4)0.0f;

  const unsigned short* Abase = A + (size_t)mt * 128 * 512;
  const unsigned short* Bbase = Bt + (size_t)nt * 128 * 512;

  for (int k0 = 0; k0 < 512; k0 += 64) {
    __syncthreads();  // previous tile fully consumed
#pragma unroll
    for (int i = 0; i < 4; ++i) {
      int e = (i * 256 + tid) * 8;  // element index in 128x64 tile
      int r = e >> 6, kk = e & 63;
      __builtin_amdgcn_global_load_lds(
          (const __attribute__((address_space(1))) void*)(Abase + (size_t)r * 512 + k0 + kk),
          (__attribute__((address_space(3))) void*)(&As[e]), 16, 0, 0);
      __builtin_amdgcn_global_load_lds(
          (const __attribute__((address_space(1))) void*)(Bbase + (size_t)r * 512 + k0 + kk),
          (__attribute__((address_space(3))) void*)(&Bs[e]), 16, 0, 0);
    }
    __syncthreads();  // drains vmcnt(0): tile resident
#pragma unroll
    for (int ks = 0; ks < 2; ++ks) {
      bf16x8 av[4], bv[4];
#pragma unroll
      for (int i = 0; i < 4; ++i)
        av[i] = *reinterpret_cast<const bf16x8*>(
            &As[(wr * 64 + i * 16 + rl) * 64 + ks * 32 + kg * 8]);
#pragma unroll
      for (int j = 0; j < 4; ++j)
        bv[j] = *reinterpret_cast<const bf16x8*>(
            &Bs[(wc * 64 + j * 16 + rl) * 64 + ks * 32 + kg * 8]);
#pragma unroll
      for (int i = 0; i < 4; ++i)
#pragma unroll
        for (int j = 0; j < 4; ++j)
          acc[i][j] = __builtin_amdgcn_mfma_f32_16x16x32_bf16(av[i], bv[j], acc[i][j], 0, 0, 0);
    }
  }

  // epilogue: D[row=(l>>4)*4+r][col=l&15] per frag
  const int rowb = mt * 128 + wr * 64 + kg * 4;
  const int colb = nt * 128 + wc * 64 + rl;
#pragma unroll
  for (int i = 0; i < 4; ++i) {
#pragma unroll
    for (int j = 0; j < 4; ++j) {
      int col = colb + j * 16;
      float bb = bias[col];
#pragma unroll
      for (int r = 0; r < 4; ++r) {
        int row = rowb + i * 16 + r;
        float v = acc[i][j][r] + bb;
        if (OUT_BF16)
          ((unsigned short*)out)[(size_t)row * NOUT + col] = f2bf(v);
        else
          ((float*)out)[(size_t)row * NOUT + col] = v;
      }
    }
  }
}

// ---------------- k4: attention ----------------
// Block = 128 threads (2 waves), each wave one (b, h). Lane = query token i.
// K/V staged fp32 in LDS; all j-loops FULLY unrolled so S[] stays in VGPRs
// (partial unroll would runtime-index S -> scratch, rule #20).
__global__ __launch_bounds__(128) void attn_kernel(
    const unsigned short* __restrict__ qkvb, const float* __restrict__ mask,
    const float* __restrict__ rpb, unsigned short* __restrict__ attnb) {
  __shared__ __attribute__((aligned(16))) float kv[2][2][64][36];
  const int bid = blockIdx.x;
  const int b = bid >> 3, hg = bid & 7;
  const int w = threadIdx.x >> 6, l = threadIdx.x & 63;
  const int h = hg * 2 + w;
  const size_t rowbase = (size_t)(b * 64 + l) * 1536;

  // stage K and V rows (lane l -> token row l), bf16 -> fp32
  {
    const ushort4* kp = (const ushort4*)(qkvb + rowbase + 512 + h * 32);
    const ushort4* vp = (const ushort4*)(qkvb + rowbase + 1024 + h * 32);
#pragma unroll
    for (int c = 0; c < 8; ++c) {
      ushort4 kq = kp[c], vq = vp[c];
      float4 kf = make_float4(bf2f(kq.x), bf2f(kq.y), bf2f(kq.z), bf2f(kq.w));
      float4 vf = make_float4(bf2f(vq.x), bf2f(vq.y), bf2f(vq.z), bf2f(vq.w));
      *(float4*)&kv[w][0][l][c * 4] = kf;
      *(float4*)&kv[w][1][l][c * 4] = vf;
    }
  }

  // q row into regs, pre-scaled
  float q[32];
  {
    const ushort4* qp = (const ushort4*)(qkvb + rowbase + h * 32);
#pragma unroll
    for (int c = 0; c < 8; ++c) {
      ushort4 t = qp[c];
      q[c * 4 + 0] = bf2f(t.x) * SCALE;
      q[c * 4 + 1] = bf2f(t.y) * SCALE;
      q[c * 4 + 2] = bf2f(t.z) * SCALE;
      q[c * 4 + 3] = bf2f(t.w) * SCALE;
    }
  }
  // No __syncthreads needed: each wave reads only its own LDS slice; same-wave
  // write->read ordering is enforced by compiler-inserted lgkmcnt waits.

  const int yi = l >> 3, xi = l & 7;
  const float* mrow = mask + (size_t)(b & 63) * 4096 + l * 64;

  float S[64];
#pragma unroll
  for (int j = 0; j < 64; ++j) {
    const float* kr = &kv[w][0][j][0];  // wave-uniform addr -> LDS broadcast
    float s = 0.f;
#pragma unroll
    for (int d = 0; d < 32; ++d) s = fmaf(q[d], kr[d], s);
    int yj = j >> 3, xj = j & 7;
    int ridx = (yi - yj + 7) * 15 + (xi - xj + 7);
    s += rpb[ridx * 16 + h] + mrow[j];
    S[j] = s;
  }

  // softmax over lane-private row
  float m = S[0];
#pragma unroll
  for (int j = 1; j < 64; ++j) m = fmaxf(m, S[j]);
  float sum = 0.f;
#pragma unroll
  for (int j = 0; j < 64; ++j) {
    S[j] = __expf(S[j] - m);
    sum += S[j];
  }
  float inv = 1.f / sum;

  float O[32];
#pragma unroll
  for (int d = 0; d < 32; ++d) O[d] = 0.f;
#pragma unroll
  for (int j = 0; j < 64; ++j) {
    const float* vr = &kv[w][1][j][0];
    float p = S[j];
#pragma unroll
    for (int d = 0; d < 32; ++d) O[d] = fmaf(p, vr[d], O[d]);
  }

  ushort4* op = (ushort4*)(attnb + (size_t)(b * 64 + l) * 512 + h * 32);
#pragma unroll
  for (int c = 0; c < 8; ++c) {
    ushort4 o;
    o.x = f2bf(O[c * 4 + 0] * inv);
    o.y = f2bf(O[c * 4 + 1] * inv);
    o.z = f2bf(O[c * 4 + 2] * inv);
    o.w = f2bf(O[c * 4 + 3] * inv);
    op[c] = o;
  }
}

extern "C" void kernel_launch(void* const* d_in, const int* in_sizes, int n_in,
                              void* d_out, int out_size, void* d_ws, size_t ws_size,
                              hipStream_t stream) {
  const float* x      = (const float*)d_in[0];
  const float* mask   = (const float*)d_in[1];
  const float* qkv_w  = (const float*)d_in[2];
  const float* qkv_b  = (const float*)d_in[3];
  const float* rpb    = (const float*)d_in[4];
  const float* proj_w = (const float*)d_in[5];
  const float* proj_b = (const float*)d_in[6];

  char* ws = (char*)d_ws;
  unsigned short* qkvb   = (unsigned short*)ws;                    // 402,653,184 B
  unsigned short* xb     = (unsigned short*)(ws + 402653184);      // 134,217,728 B
  unsigned short* attnb  = xb;  // alias: xb is dead after the QKV GEMM
  unsigned short* wqkvT  = (unsigned short*)(ws + 536870912);      // 1,572,864 B
  unsigned short* wprojT = (unsigned short*)(ws + 538443776);      //   524,288 B

  cast_x_kernel<<<65536, 256, 0, stream>>>(x, xb);
  castT_kernel<<<3072, 256, 0, stream>>>(qkv_w, wqkvT, 1536);
  castT_kernel<<<1024, 256, 0, stream>>>(proj_w, wprojT, 512);
  gemm_kernel<1536, true><<<12288, 256, 0, stream>>>(xb, wqkvT, qkv_b, qkvb);
  attn_kernel<<<16384, 128, 0, stream>>>(qkvb, mask, rpb, attnb);
  gemm_kernel<512, false><<<4096, 256, 0, stream>>>(attnb, wprojT, proj_b, d_out);
}

// Round 3
// 1149.008 us; speedup vs baseline: 1.3636x; 1.3636x over previous
//
#include <hip/hip_runtime.h>

// ProgressiveWindowAttention — Swin-style window MHA.
// B=2048 windows, N=64 tokens, C=512, H=16 heads, HD=32, NW=64, W=8.
//
// Pipeline:
//   k0: cast x fp32 -> bf16                       (xb)
//   k1: transpose+cast qkv_w -> [1536][512] bf16  (wqkvT)
//   k2: transpose+cast proj_w -> [512][512] bf16  (wprojT)
//   k3: QKV GEMM  bf16 MFMA 128x128 tile (XCD-swizzled grid) -> qkvb bf16
//   k4: biasT[h][i][j] = rpb[rel(i,j)][h]  (262KB, reuses dead wqkvT region)
//   k5: attention: 1 wave per (b,h), MFMA QK^T + exp + MFMA PV.
//       Q/K frags direct from global; V^T and P staged in XOR-swizzled LDS.
//   k6: proj GEMM bf16 MFMA -> d_out fp32 (+bias)
//
// ws layout (539 MB, unchanged from round 2 which passed):
//   [0, 402653184)            qkvb  [131072][1536] bf16
//   [402653184, 536870912)    xb    [131072][512]  bf16  (reused as attnb)
//   [536870912, 538443776)    wqkvT [1536][512]    bf16  (reused as biasT f32)
//   [538443776, 538968064)    wprojT[512][512]     bf16

#define SCALE 0.17677669529663689f  // 32^-0.5

typedef __bf16 bf16x8 __attribute__((ext_vector_type(8)));
typedef float f32x4 __attribute__((ext_vector_type(4)));
typedef unsigned short ushortx8 __attribute__((ext_vector_type(8)));

__device__ __forceinline__ unsigned short f2bf(float f) {
  unsigned u = __builtin_bit_cast(unsigned, f);
  u += 0x7FFFu + ((u >> 16) & 1u);   // RNE
  return (unsigned short)(u >> 16);
}

__device__ __forceinline__ float fast_rcp(float x) {
#if __has_builtin(__builtin_amdgcn_rcpf)
  return __builtin_amdgcn_rcpf(x);
#else
  return 1.0f / x;
#endif
}

// ---------------- k0: cast x to bf16 (4 elems/thread) ----------------
__global__ __launch_bounds__(256) void cast_x_kernel(
    const float* __restrict__ x, unsigned short* __restrict__ xb) {
  int idx = blockIdx.x * 256 + threadIdx.x;
  float4 v = ((const float4*)x)[idx];
  ushort4 o;
  o.x = f2bf(v.x); o.y = f2bf(v.y); o.z = f2bf(v.z); o.w = f2bf(v.w);
  ((ushort4*)xb)[idx] = o;
}

// ------------- k1/k2: W [512][Nc] fp32 -> W^T [Nc][512] bf16 -------------
__global__ __launch_bounds__(256) void castT_kernel(
    const float* __restrict__ w, unsigned short* __restrict__ wT, int Nc) {
  int o = blockIdx.x * 256 + threadIdx.x;  // o = n*512 + k
  int n = o >> 9, k = o & 511;
  wT[o] = f2bf(w[(size_t)k * Nc + n]);
}

// ------------- k4: biasT[h][i][j] = rpb[rel(i,j)*16 + h] -------------
__global__ __launch_bounds__(256) void bias_kernel(
    const float* __restrict__ rpb, float* __restrict__ biasT) {
  int idx = blockIdx.x * 256 + threadIdx.x;  // h*4096 + i*64 + j
  int h = idx >> 12, ij = idx & 4095, i = ij >> 6, j = ij & 63;
  int ridx = ((i >> 3) - (j >> 3) + 7) * 15 + ((i & 7) - (j & 7) + 7);
  biasT[idx] = rpb[ridx * 16 + h];
}

// ---------------- GEMM: A[M][512]bf16 @ Bt[NOUT][512]bf16 ----------------
// 128x128 tile, BK=64, 4 waves (2x2), each wave 64x64 = 4x4 frags of 16x16.
// Grid is XCD-swizzled (grid%8==0): each XCD gets a contiguous bid chunk ->
// A-panel reuse in its private L2, B fully L2-resident.
template <int NOUT, bool OUT_BF16>
__global__ __launch_bounds__(256) void gemm_kernel(
    const unsigned short* __restrict__ A, const unsigned short* __restrict__ Bt,
    const float* __restrict__ bias, void* __restrict__ out) {
  __shared__ __attribute__((aligned(16))) unsigned short As[128 * 64];
  __shared__ __attribute__((aligned(16))) unsigned short Bs[128 * 64];
  constexpr int NT = NOUT / 128;
  const int cpx = gridDim.x >> 3;
  const int bid = (blockIdx.x & 7) * cpx + (blockIdx.x >> 3);  // XCD swizzle
  const int mt = bid / NT, nt = bid % NT;
  const int tid = threadIdx.x;
  const int w = tid >> 6, l = tid & 63;
  const int wr = w >> 1, wc = w & 1;
  const int rl = l & 15, kg = l >> 4;

  f32x4 acc[4][4];
#pragma unroll
  for (int i = 0; i < 4; ++i)
#pragma unroll
    for (int j = 0; j < 4; ++j) acc[i][j] = (f32x4)0.0f;

  const unsigned short* Abase = A + (size_t)mt * 128 * 512;
  const unsigned short* Bbase = Bt + (size_t)nt * 128 * 512;

  for (int k0 = 0; k0 < 512; k0 += 64) {
    __syncthreads();  // previous tile fully consumed
#pragma unroll
    for (int i = 0; i < 4; ++i) {
      int e = (i * 256 + tid) * 8;  // element index in 128x64 tile
      int r = e >> 6, kk = e & 63;
      __builtin_amdgcn_global_load_lds(
          (const __attribute__((address_space(1))) void*)(Abase + (size_t)r * 512 + k0 + kk),
          (__attribute__((address_space(3))) void*)(&As[e]), 16, 0, 0);
      __builtin_amdgcn_global_load_lds(
          (const __attribute__((address_space(1))) void*)(Bbase + (size_t)r * 512 + k0 + kk),
          (__attribute__((address_space(3))) void*)(&Bs[e]), 16, 0, 0);
    }
    __syncthreads();  // drains vmcnt(0): tile resident
#pragma unroll
    for (int ks = 0; ks < 2; ++ks) {
      bf16x8 av[4], bv[4];
#pragma unroll
      for (int i = 0; i < 4; ++i)
        av[i] = *reinterpret_cast<const bf16x8*>(
            &As[(wr * 64 + i * 16 + rl) * 64 + ks * 32 + kg * 8]);
#pragma unroll
      for (int j = 0; j < 4; ++j)
        bv[j] = *reinterpret_cast<const bf16x8*>(
            &Bs[(wc * 64 + j * 16 + rl) * 64 + ks * 32 + kg * 8]);
#pragma unroll
      for (int i = 0; i < 4; ++i)
#pragma unroll
        for (int j = 0; j < 4; ++j)
          acc[i][j] = __builtin_amdgcn_mfma_f32_16x16x32_bf16(av[i], bv[j], acc[i][j], 0, 0, 0);
    }
  }

  // epilogue: D[row=(l>>4)*4+r][col=l&15] per frag
  const int rowb = mt * 128 + wr * 64 + kg * 4;
  const int colb = nt * 128 + wc * 64 + rl;
#pragma unroll
  for (int i = 0; i < 4; ++i) {
#pragma unroll
    for (int j = 0; j < 4; ++j) {
      int col = colb + j * 16;
      float bb = bias[col];
#pragma unroll
      for (int r = 0; r < 4; ++r) {
        int row = rowb + i * 16 + r;
        float v = acc[i][j][r] + bb;
        if (OUT_BF16)
          ((unsigned short*)out)[(size_t)row * NOUT + col] = f2bf(v);
        else
          ((float*)out)[(size_t)row * NOUT + col] = v;
      }
    }
  }
}

// ---------------- k5: MFMA attention ----------------
// Block = 256 threads = 4 waves; wave = one (b, h). No barriers (wave-private
// LDS slices). LDS/wave: Vt[32][64] bf16 (4KB) + P[64][64] bf16 (8KB), both
// XOR-swizzled (elem ^= (row&7)<<3) to kill the stride-128B bank conflict.
__global__ __launch_bounds__(256) void attn_mfma_kernel(
    const unsigned short* __restrict__ qkvb, const float* __restrict__ mask,
    const float* __restrict__ biasT, unsigned short* __restrict__ attnb) {
  __shared__ __attribute__((aligned(16))) unsigned short lds[4 * 6144];
  const int wv = threadIdx.x >> 6, l = threadIdx.x & 63;
  const int wid = blockIdx.x * 4 + wv;
  const int b = wid >> 4, h = wid & 15;
  const int rl = l & 15, kg = l >> 4;
  const size_t tokbase = (size_t)b * 64;

  unsigned short* Vt = &lds[wv * 6144];         // [32][64] swizzled
  unsigned short* P  = &lds[wv * 6144 + 2048];  // [64][64] swizzled

  // ---- stage V^T (lane l owns token l; 32 b16 scatter writes, 2-way-free) ----
  {
    const ushortx8* vp = (const ushortx8*)(qkvb + (tokbase + l) * 1536 + 1024 + h * 32);
    ushortx8 vv[4];
#pragma unroll
    for (int c = 0; c < 4; ++c) vv[c] = vp[c];
#pragma unroll
    for (int c = 0; c < 4; ++c)
#pragma unroll
      for (int d = 0; d < 8; ++d)
        Vt[(((c * 8 + d) * 64) + l) ^ (d << 3)] = vv[c][d];
  }

  // ---- Q and K fragments straight from global (token rows are frag-ordered) ----
  bf16x8 aq[4], bk[4];
#pragma unroll
  for (int t = 0; t < 4; ++t) {
    aq[t] = *(const bf16x8*)(qkvb + (tokbase + t * 16 + rl) * 1536 + h * 32 + kg * 8);
    bk[t] = *(const bf16x8*)(qkvb + (tokbase + t * 16 + rl) * 1536 + 512 + h * 32 + kg * 8);
  }

  // ---- QK^T: 16 MFMAs, S tile (ti,tj): row=ti*16+kg*4+r, col=tj*16+rl ----
  f32x4 acc[4][4];
#pragma unroll
  for (int ti = 0; ti < 4; ++ti)
#pragma unroll
    for (int tj = 0; tj < 4; ++tj)
      acc[ti][tj] = __builtin_amdgcn_mfma_f32_16x16x32_bf16(aq[ti], bk[tj], (f32x4)0.0f, 0, 0, 0);

  // ---- logits + exp (no max-sub: |logit| << 88) + row-sum + P writes ----
  const float* mrow = mask + (size_t)(b & 63) * 4096;
  const float* brow = biasT + (size_t)h * 4096;
  float rs[4][4];
#pragma unroll
  for (int ti = 0; ti < 4; ++ti)
#pragma unroll
    for (int r = 0; r < 4; ++r) rs[ti][r] = 0.f;

#pragma unroll
  for (int ti = 0; ti < 4; ++ti) {
#pragma unroll
    for (int tj = 0; tj < 4; ++tj) {
#pragma unroll
      for (int r = 0; r < 4; ++r) {
        int i = ti * 16 + kg * 4 + r, j = tj * 16 + rl;
        int ix = i * 64 + j;
        float lg = fmaf(acc[ti][tj][r], SCALE, mrow[ix] + brow[ix]);
        float p = __expf(lg);
        rs[ti][r] += p;
        P[ix ^ ((i & 7) << 3)] = f2bf(p);
      }
    }
  }

  // ---- finish row sums across the 16-lane rl group; keep reciprocal ----
#pragma unroll
  for (int ti = 0; ti < 4; ++ti)
#pragma unroll
    for (int r = 0; r < 4; ++r) {
      float s = rs[ti][r];
      s += __shfl_xor(s, 1); s += __shfl_xor(s, 2);
      s += __shfl_xor(s, 4); s += __shfl_xor(s, 8);
      rs[ti][r] = fast_rcp(s);
    }

  // ---- PV: O tile (ti,dt), K=64 over kt; A=P frags, B=V^T frags ----
  f32x4 o[4][2];
#pragma unroll
  for (int ti = 0; ti < 4; ++ti)
#pragma unroll
    for (int dt = 0; dt < 2; ++dt) o[ti][dt] = (f32x4)0.0f;

#pragma unroll
  for (int kt = 0; kt < 2; ++kt) {
    bf16x8 pa[4], bv[2];
#pragma unroll
    for (int ti = 0; ti < 4; ++ti) {
      int row = ti * 16 + rl;
      pa[ti] = *(const bf16x8*)&P[(row * 64 + kt * 32 + kg * 8) ^ ((row & 7) << 3)];
    }
#pragma unroll
    for (int dt = 0; dt < 2; ++dt) {
      int d = dt * 16 + rl;
      bv[dt] = *(const bf16x8*)&Vt[(d * 64 + kt * 32 + kg * 8) ^ ((d & 7) << 3)];
    }
#pragma unroll
    for (int ti = 0; ti < 4; ++ti)
#pragma unroll
      for (int dt = 0; dt < 2; ++dt)
        o[ti][dt] = __builtin_amdgcn_mfma_f32_16x16x32_bf16(pa[ti], bv[dt], o[ti][dt], 0, 0, 0);
  }

  // ---- normalize (deferred 1/sum) + store bf16 ----
  unsigned short* ob = attnb + tokbase * 512 + h * 32;
#pragma unroll
  for (int ti = 0; ti < 4; ++ti)
#pragma unroll
    for (int dt = 0; dt < 2; ++dt)
#pragma unroll
      for (int r = 0; r < 4; ++r) {
        int i = ti * 16 + kg * 4 + r;
        ob[(size_t)i * 512 + dt * 16 + rl] = f2bf(o[ti][dt][r] * rs[ti][r]);
      }
}

extern "C" void kernel_launch(void* const* d_in, const int* in_sizes, int n_in,
                              void* d_out, int out_size, void* d_ws, size_t ws_size,
                              hipStream_t stream) {
  const float* x      = (const float*)d_in[0];
  const float* mask   = (const float*)d_in[1];
  const float* qkv_w  = (const float*)d_in[2];
  const float* qkv_b  = (const float*)d_in[3];
  const float* rpb    = (const float*)d_in[4];
  const float* proj_w = (const float*)d_in[5];
  const float* proj_b = (const float*)d_in[6];

  char* ws = (char*)d_ws;
  unsigned short* qkvb   = (unsigned short*)ws;                    // 402,653,184 B
  unsigned short* xb     = (unsigned short*)(ws + 402653184);      // 134,217,728 B
  unsigned short* attnb  = xb;  // alias: xb is dead after the QKV GEMM
  unsigned short* wqkvT  = (unsigned short*)(ws + 536870912);      // 1,572,864 B
  float*          biasT  = (float*)(ws + 536870912);               // 262,144 B (after QKV GEMM)
  unsigned short* wprojT = (unsigned short*)(ws + 538443776);      //   524,288 B

  cast_x_kernel<<<65536, 256, 0, stream>>>(x, xb);
  castT_kernel<<<3072, 256, 0, stream>>>(qkv_w, wqkvT, 1536);
  castT_kernel<<<1024, 256, 0, stream>>>(proj_w, wprojT, 512);
  gemm_kernel<1536, true><<<12288, 256, 0, stream>>>(xb, wqkvT, qkv_b, qkvb);
  bias_kernel<<<256, 256, 0, stream>>>(rpb, biasT);          // overwrites dead wqkvT
  attn_mfma_kernel<<<8192, 256, 0, stream>>>(qkvb, mask, biasT, attnb);
  gemm_kernel<512, false><<<4096, 256, 0, stream>>>(attnb, wprojT, proj_b, d_out);
}